// Round 15
// baseline (47.767 us; speedup 1.0000x reference)
//
#include <hip/hip_runtime.h>
#include <math.h>

typedef __bf16 bf16x8 __attribute__((ext_vector_type(8)));
typedef float f32x4 __attribute__((ext_vector_type(4)));
typedef unsigned short u16x8 __attribute__((ext_vector_type(8)));

#define N_TOT 8192
#define HALF_N 4096
#define D 128
#define INV_T 14.285714285714286f
#define CSC 20.609929155556627f    /* (1/0.07) * log2(e) */
#define NCSC -20.609929155556627f
#define LN2F 0.69314718055994531f
#define NEG_BIG -3.0e38f
#define M_INIT -1.0e30f
#define THR_RAW 1.0f                /* defer-max slack (raw units) */
#define CS 16                       /* col groups of 512 = 32 tiles */

__device__ __forceinline__ unsigned short f2bf(float f) {
    union { float f; unsigned int u; } a; a.f = f;
    unsigned int u = a.u;
    return (unsigned short)((u + 0x7fffu + ((u >> 16) & 1u)) >> 16);
}

// ---------- kernel 1: fp32 -> bf16 packed in MFMA-fragment order ----------
// fbP chunk c (16B): c = (T*4 + kk)*64 + lg*16 + lr  holds
// F[col = T*16 + lr][kk*32 + lg*8 .. +8]; a (tile,kk) wave-load is one
// contiguous 1KB read; 4 consecutive tiles are a contiguous 16 KB span.
__global__ __launch_bounds__(256)
void cvt_kernel(const float* __restrict__ in, unsigned short* __restrict__ fbP) {
    const int c   = blockIdx.x * 256 + threadIdx.x;
    const int q   = c >> 6;
    const int rem = c & 63;
    const int lg  = rem >> 4, lr = rem & 15;
    const int kk  = q & 3;
    const int col = (q >> 2) * 16 + lr;
    const int j16 = kk * 4 + lg;
    const float4 v0 = reinterpret_cast<const float4*>(in)[col * 32 + j16 * 2];
    const float4 v1 = reinterpret_cast<const float4*>(in)[col * 32 + j16 * 2 + 1];
    u16x8 o;
    o[0] = f2bf(v0.x); o[1] = f2bf(v0.y); o[2] = f2bf(v0.z); o[3] = f2bf(v0.w);
    o[4] = f2bf(v1.x); o[5] = f2bf(v1.y); o[6] = f2bf(v1.z); o[7] = f2bf(v1.w);
    reinterpret_cast<u16x8*>(fbP)[c] = o;
}

// ---------- kernel 2: fused sim + online logsumexp, counted-wait pipeline ----------
// grid (32 rowgroups, 16 colgroups), 256 thr = 4 waves. Wave w HOLDS rows
// [rg*256 + w*64, +64). Block stages 16 KB (4 col-tiles) per phase via
// global_load_lds, double-buffered. Phase = [vmcnt(0) on OLD stage (covered
// by prior phase's compute) ; raw s_barrier (visibility, no drain) ;
// ds_read + issue next stage + compute]. No __syncthreads drains anywhere.
__global__ __launch_bounds__(256)
void simclr_kernel(const unsigned short* __restrict__ fbP,
                   float* __restrict__ pm, float* __restrict__ ps) {
    __shared__ __align__(16) unsigned short lds[2][8192];   // 2 x 16 KB
    const int tid  = threadIdx.x;
    const int lane = tid & 63;
    const int wid  = tid >> 6;              // 0..3
    const int lr   = lane & 15;
    const int lg   = lane >> 4;
    const int RT0  = blockIdx.x * 16 + wid * 4;   // first held row-tile
    const int Tw   = blockIdx.y * 32;             // first streamed col-tile

    // held rows: 4 row-tiles (distinct per wave), loaded once from L2
    bf16x8 br[4][4];
#pragma unroll
    for (int rt = 0; rt < 4; ++rt)
#pragma unroll
        for (int kk = 0; kk < 4; ++kk)
            br[rt][kk] = *reinterpret_cast<const bf16x8*>(
                fbP + ((size_t)(((RT0 + rt) * 4 + kk) * 64) + lane) * 8);

    float m[4], s[4];
#pragma unroll
    for (int rt = 0; rt < 4; ++rt) { m[rt] = M_INIT; s[rt] = 0.f; }

    // stage phase q's 16 KB (tiles Tw+4q .. +3) -> lds[b]: linear both sides
    auto stage = [&](int q, int b) {
#pragma unroll
        for (int h = 0; h < 4; ++h) {
            const unsigned short* src =
                fbP + ((size_t)(Tw + 4 * q + h) * 256 + tid) * 8;
            unsigned short* dst = &lds[b][(h * 256 + tid) * 8];
            __builtin_amdgcn_global_load_lds(
                (const __attribute__((address_space(1))) unsigned int*)(const void*)src,
                (__attribute__((address_space(3))) unsigned int*)(void*)dst,
                16, 0, 0);
        }
    };

    stage(0, 0);

    int buf = 0;
#pragma unroll 1
    for (int q = 0; q < 8; ++q) {
        // wait for stage(q) (issued a full phase ago -> latency already hidden),
        // then raw barrier: all waves' stage parts visible. No drain of new work.
        __builtin_amdgcn_sched_barrier(0);
        asm volatile("s_waitcnt vmcnt(0)" ::: "memory");
        __builtin_amdgcn_s_barrier();
        asm volatile("" ::: "memory");
        __builtin_amdgcn_sched_barrier(0);

#pragma unroll
        for (int pp = 0; pp < 2; ++pp) {
            const unsigned short* B = &lds[buf][pp * 4096];
            bf16x8 ca[4], cb[4];
#pragma unroll
            for (int kk = 0; kk < 4; ++kk) {
                ca[kk] = *reinterpret_cast<const bf16x8*>(&B[(kk * 64 + lane) * 8]);
                cb[kk] = *reinterpret_cast<const bf16x8*>(&B[((kk + 4) * 64 + lane) * 8]);
            }
            if (pp == 0 && q < 7) stage(q + 1, buf ^ 1);   // writes OTHER buffer

            const int c0 = blockIdx.y * 512 + (q * 4 + pp * 2) * 16;  // [c0, c0+32)

            f32x4 accP[4], accQ[4];
#pragma unroll
            for (int rt = 0; rt < 4; ++rt) accP[rt] = f32x4{0.f, 0.f, 0.f, 0.f};
#pragma unroll
            for (int kk = 0; kk < 4; ++kk)
#pragma unroll
                for (int rt = 0; rt < 4; ++rt)
                    accP[rt] = __builtin_amdgcn_mfma_f32_16x16x32_bf16(ca[kk], br[rt][kk], accP[rt], 0, 0, 0);
#pragma unroll
            for (int rt = 0; rt < 4; ++rt) accQ[rt] = f32x4{0.f, 0.f, 0.f, 0.f};
#pragma unroll
            for (int kk = 0; kk < 4; ++kk)
#pragma unroll
                for (int rt = 0; rt < 4; ++rt)
                    accQ[rt] = __builtin_amdgcn_mfma_f32_16x16x32_bf16(cb[kk], br[rt][kk], accQ[rt], 0, 0, 0);

            // merged pair epilogue: lane's elems = sim[rowbase+lr][c0 + lg*4+r (+16)]
#pragma unroll
            for (int rt = 0; rt < 4; ++rt) {
                const int rowbase = (RT0 + rt) * 16;
                f32x4 P = accP[rt], Q = accQ[rt];
                if (c0 == rowbase) {                  // wave-uniform: diagonal tile
#pragma unroll
                    for (int r = 0; r < 4; ++r)
                        if (lr == lg * 4 + r) P[r] = NEG_BIG;
                }
                if (c0 + 16 == rowbase) {
#pragma unroll
                    for (int r = 0; r < 4; ++r)
                        if (lr == lg * 4 + r) Q[r] = NEG_BIG;
                }
                const float t1 = fmaxf(fmaxf(P[0], P[1]), P[2]);
                const float t2 = fmaxf(fmaxf(P[3], Q[0]), Q[1]);
                const float t3 = fmaxf(Q[2], Q[3]);
                const float rmax = fmaxf(fmaxf(t1, t2), t3);
                // defer-max: rescale only when some lane exceeds m+THR
                if (!__all(rmax <= m[rt] + THR_RAW)) {
                    const float mn = fmaxf(m[rt], rmax);
                    s[rt] *= __builtin_amdgcn_exp2f(fmaf(m[rt], CSC, mn * NCSC));
                    m[rt] = mn;
                }
                const float cm = m[rt] * NCSC;
                const float e0 = __builtin_amdgcn_exp2f(fmaf(P[0], CSC, cm));
                const float e1 = __builtin_amdgcn_exp2f(fmaf(P[1], CSC, cm));
                const float e2 = __builtin_amdgcn_exp2f(fmaf(P[2], CSC, cm));
                const float e3 = __builtin_amdgcn_exp2f(fmaf(P[3], CSC, cm));
                const float e4 = __builtin_amdgcn_exp2f(fmaf(Q[0], CSC, cm));
                const float e5 = __builtin_amdgcn_exp2f(fmaf(Q[1], CSC, cm));
                const float e6 = __builtin_amdgcn_exp2f(fmaf(Q[2], CSC, cm));
                const float e7 = __builtin_amdgcn_exp2f(fmaf(Q[3], CSC, cm));
                s[rt] += ((e0 + e1) + (e2 + e3)) + ((e4 + e5) + (e6 + e7));
            }
        }
        buf ^= 1;
    }

    // per-wave row-reduce: lanes sharing a row differ only in lg (xor 16,32)
#pragma unroll
    for (int rt = 0; rt < 4; ++rt) {
        float M = m[rt];
        M = fmaxf(M, __shfl_xor(M, 16, 64));
        M = fmaxf(M, __shfl_xor(M, 32, 64));
        float sc = s[rt] * __builtin_amdgcn_exp2f(fmaf(m[rt], CSC, M * NCSC));
        sc += __shfl_xor(sc, 16, 64);
        sc += __shfl_xor(sc, 32, 64);
        if (lg == 0) {
            const int row = (RT0 + rt) * 16 + lr;
            pm[blockIdx.y * N_TOT + row] = M;
            ps[blockIdx.y * N_TOT + row] = sc;
        }
    }
}

// ---------- kernel 3: merge partials + fp32 positive dot + mean (32 blocks) ----------
__global__ __launch_bounds__(256)
void rowloss_mean_kernel(const float* __restrict__ pm, const float* __restrict__ ps,
                         const float* __restrict__ feat, float* __restrict__ out) {
    const int row = blockIdx.x * 256 + threadIdx.x;
    float M = pm[row], S = ps[row];
#pragma unroll
    for (int c = 1; c < CS; ++c) {
        const float Mo = pm[c * N_TOT + row], So = ps[c * N_TOT + row];
        const float mn = fmaxf(M, Mo);
        S = fmaf(S,  __builtin_amdgcn_exp2f(fmaf(M,  CSC, mn * NCSC)),
                 So * __builtin_amdgcn_exp2f(fmaf(Mo, CSC, mn * NCSC)));
        M = mn;
    }
    // positive in fp32 straight from the original features
    const float4* f = reinterpret_cast<const float4*>(feat + (size_t)row * D);
    const float4* g = reinterpret_cast<const float4*>(feat + (size_t)(row ^ HALF_N) * D);
    float dot = 0.f;
#pragma unroll
    for (int j = 0; j < 32; ++j) {
        const float4 a = f[j], b = g[j];
        dot += a.x * b.x + a.y * b.y + a.z * b.z + a.w * b.w;
    }
    float acc = LN2F * fmaf(M, CSC, __builtin_amdgcn_logf(S)) - dot * INV_T;
#pragma unroll
    for (int off = 32; off > 0; off >>= 1) acc += __shfl_xor(acc, off, 64);
    __shared__ float ls[4];
    if ((threadIdx.x & 63) == 0) ls[threadIdx.x >> 6] = acc;
    __syncthreads();
    if (threadIdx.x == 0)
        atomicAdd(out, (ls[0] + ls[1] + ls[2] + ls[3]) * (1.0f / (float)N_TOT));
}

extern "C" void kernel_launch(void* const* d_in, const int* in_sizes, int n_in,
                              void* d_out, int out_size, void* d_ws, size_t ws_size,
                              hipStream_t stream) {
    const float* feat = (const float*)d_in[0];
    char* ws = (char*)d_ws;
    unsigned short* fbP = (unsigned short*)ws;                                  // 2 MB
    float* pm      = (float*)(ws + (size_t)N_TOT * D * 2);                      // 512 KB
    float* ps      = (float*)(ws + (size_t)N_TOT * D * 2 + (size_t)CS * N_TOT * 4);       // 512 KB
    float* out = (float*)d_out;

    hipMemsetAsync(out, 0, sizeof(float), stream);
    cvt_kernel<<<512, 256, 0, stream>>>(feat, fbP);
    simclr_kernel<<<dim3(32, CS), 256, 0, stream>>>(fbP, pm, ps);
    rowloss_mean_kernel<<<N_TOT / 256, 256, 0, stream>>>(pm, ps, feat, out);
}

// Round 16
// 45.520 us; speedup vs baseline: 1.0494x; 1.0494x over previous
//
#include <hip/hip_runtime.h>
#include <math.h>

typedef __bf16 bf16x8 __attribute__((ext_vector_type(8)));
typedef float f32x4 __attribute__((ext_vector_type(4)));
typedef unsigned short u16x8 __attribute__((ext_vector_type(8)));

#define N_TOT 8192
#define HALF_N 4096
#define D 128
#define INV_T 14.285714285714286f
#define CSC 20.609929155556627f    /* (1/0.07) * log2(e) */
#define NCSC -20.609929155556627f
#define LN2F 0.69314718055994531f
#define NEG_BIG -3.0e38f
#define M_INIT -1.0e30f
#define THR_RAW 1.0f                /* defer-max slack (raw units) */
#define CS 16                       /* col groups of 512 = 16 pairs */

__device__ __forceinline__ unsigned short f2bf(float f) {
    union { float f; unsigned int u; } a; a.f = f;
    unsigned int u = a.u;
    return (unsigned short)((u + 0x7fffu + ((u >> 16) & 1u)) >> 16);
}

// ---------- kernel 1: fp32 -> bf16 packed in MFMA-fragment order ----------
// fbP chunk c (16B): c = (T*4 + kk)*64 + lg*16 + lr  holds
// F[col = T*16 + lr][kk*32 + lg*8 .. +8]; a tile-pair is a contiguous 8 KB.
// Thread (0,0) also zero-inits the output accumulator (replaces memset node).
__global__ __launch_bounds__(256)
void cvt_kernel(const float* __restrict__ in, unsigned short* __restrict__ fbP,
                float* __restrict__ out) {
    if (blockIdx.x == 0 && threadIdx.x == 0) out[0] = 0.f;
    const int c   = blockIdx.x * 256 + threadIdx.x;
    const int q   = c >> 6;
    const int rem = c & 63;
    const int lg  = rem >> 4, lr = rem & 15;
    const int kk  = q & 3;
    const int col = (q >> 2) * 16 + lr;
    const int j16 = kk * 4 + lg;
    const float4 v0 = reinterpret_cast<const float4*>(in)[col * 32 + j16 * 2];
    const float4 v1 = reinterpret_cast<const float4*>(in)[col * 32 + j16 * 2 + 1];
    u16x8 o;
    o[0] = f2bf(v0.x); o[1] = f2bf(v0.y); o[2] = f2bf(v0.z); o[3] = f2bf(v0.w);
    o[4] = f2bf(v1.x); o[5] = f2bf(v1.y); o[6] = f2bf(v1.z); o[7] = f2bf(v1.w);
    reinterpret_cast<u16x8*>(fbP)[c] = o;
}

// ---------- kernel 2: fused sim + online logsumexp, BARRIER-FREE pipeline ----------
// grid (32 rowgroups, 16 colgroups), 256 thr = 4 waves, 2 blocks/CU (64KB LDS).
// Wave w HOLDS rows [rg*256 + w*64, +64) and stages its OWN pair-buffers
// (2 x 8 KB private LDS) via global_load_lds; gating is per-wave counted
// s_waitcnt vmcnt(8) (stage p+1 stays in flight across the wait). No s_barrier,
// no __syncthreads, no cross-wave coupling -> waves drift/decorrelate freely.
__global__ __launch_bounds__(256, 2)
void simclr_kernel(const unsigned short* __restrict__ fbP,
                   float* __restrict__ pm, float* __restrict__ ps) {
    __shared__ __align__(16) unsigned short lds[4][2][4096];   // per-wave 2 x 8 KB
    const int tid  = threadIdx.x;
    const int lane = tid & 63;
    const int wid  = tid >> 6;              // 0..3
    const int lr   = lane & 15;
    const int lg   = lane >> 4;
    const int RT0  = blockIdx.x * 16 + wid * 4;   // first held row-tile
    const int Tw   = blockIdx.y * 32;             // first streamed col-tile

    // held rows: 4 row-tiles (distinct per wave), loaded once from L2
    bf16x8 br[4][4];
#pragma unroll
    for (int rt = 0; rt < 4; ++rt)
#pragma unroll
        for (int kk = 0; kk < 4; ++kk)
            br[rt][kk] = *reinterpret_cast<const bf16x8*>(
                fbP + ((size_t)(((RT0 + rt) * 4 + kk) * 64) + lane) * 8);

    float m[4], s[4];
#pragma unroll
    for (int rt = 0; rt < 4; ++rt) { m[rt] = M_INIT; s[rt] = 0.f; }

    // per-wave stage of pair p (8 KB = 512 chunks): 8 x global_load_lds,
    // dst = wave-uniform base + lane*16 (linear), src contiguous.
    auto stage = [&](int p, int b) {
#pragma unroll
        for (int h = 0; h < 8; ++h) {
            const unsigned short* src =
                fbP + ((size_t)(Tw + 2 * p) * 256 + h * 64 + lane) * 8;
            unsigned short* dst = &lds[wid][b][(h * 64 + lane) * 8];
            __builtin_amdgcn_global_load_lds(
                (const __attribute__((address_space(1))) unsigned int*)(const void*)src,
                (__attribute__((address_space(3))) unsigned int*)(void*)dst,
                16, 0, 0);
        }
    };

    stage(0, 0);

    int buf = 0;
#pragma unroll 1
    for (int p = 0; p < 16; ++p) {
        if (p < 15) {
            stage(p + 1, buf ^ 1);          // 16 outstanding: 8 old + 8 new
            asm volatile("s_waitcnt vmcnt(8)" ::: "memory");   // old 8 landed
        } else {
            asm volatile("s_waitcnt vmcnt(0)" ::: "memory");
        }
        __builtin_amdgcn_sched_barrier(0);

        const unsigned short* B = lds[wid][buf];
        bf16x8 ca[4], cb[4];
#pragma unroll
        for (int kk = 0; kk < 4; ++kk) {
            ca[kk] = *reinterpret_cast<const bf16x8*>(&B[(kk * 64 + lane) * 8]);
            cb[kk] = *reinterpret_cast<const bf16x8*>(&B[((kk + 4) * 64 + lane) * 8]);
        }

        const int c0 = blockIdx.y * 512 + p * 32;   // pair covers [c0, c0+32)

        f32x4 accP[4], accQ[4];
#pragma unroll
        for (int rt = 0; rt < 4; ++rt) accP[rt] = f32x4{0.f, 0.f, 0.f, 0.f};
#pragma unroll
        for (int kk = 0; kk < 4; ++kk)
#pragma unroll
            for (int rt = 0; rt < 4; ++rt)
                accP[rt] = __builtin_amdgcn_mfma_f32_16x16x32_bf16(ca[kk], br[rt][kk], accP[rt], 0, 0, 0);
#pragma unroll
        for (int rt = 0; rt < 4; ++rt) accQ[rt] = f32x4{0.f, 0.f, 0.f, 0.f};
#pragma unroll
        for (int kk = 0; kk < 4; ++kk)
#pragma unroll
            for (int rt = 0; rt < 4; ++rt)
                accQ[rt] = __builtin_amdgcn_mfma_f32_16x16x32_bf16(cb[kk], br[rt][kk], accQ[rt], 0, 0, 0);

        // merged pair epilogue: lane's elems = sim[rowbase+lr][c0 + lg*4+r (+16)]
#pragma unroll
        for (int rt = 0; rt < 4; ++rt) {
            const int rowbase = (RT0 + rt) * 16;
            f32x4 P = accP[rt], Q = accQ[rt];
            if (c0 == rowbase) {                  // wave-uniform: diagonal tile
#pragma unroll
                for (int r = 0; r < 4; ++r)
                    if (lr == lg * 4 + r) P[r] = NEG_BIG;
            }
            if (c0 + 16 == rowbase) {
#pragma unroll
                for (int r = 0; r < 4; ++r)
                    if (lr == lg * 4 + r) Q[r] = NEG_BIG;
            }
            const float t1 = fmaxf(fmaxf(P[0], P[1]), P[2]);
            const float t2 = fmaxf(fmaxf(P[3], Q[0]), Q[1]);
            const float t3 = fmaxf(Q[2], Q[3]);
            const float rmax = fmaxf(fmaxf(t1, t2), t3);
            // defer-max: rescale only when some lane exceeds m+THR
            if (!__all(rmax <= m[rt] + THR_RAW)) {
                const float mn = fmaxf(m[rt], rmax);
                s[rt] *= __builtin_amdgcn_exp2f(fmaf(m[rt], CSC, mn * NCSC));
                m[rt] = mn;
            }
            const float cm = m[rt] * NCSC;
            const float e0 = __builtin_amdgcn_exp2f(fmaf(P[0], CSC, cm));
            const float e1 = __builtin_amdgcn_exp2f(fmaf(P[1], CSC, cm));
            const float e2 = __builtin_amdgcn_exp2f(fmaf(P[2], CSC, cm));
            const float e3 = __builtin_amdgcn_exp2f(fmaf(P[3], CSC, cm));
            const float e4 = __builtin_amdgcn_exp2f(fmaf(Q[0], CSC, cm));
            const float e5 = __builtin_amdgcn_exp2f(fmaf(Q[1], CSC, cm));
            const float e6 = __builtin_amdgcn_exp2f(fmaf(Q[2], CSC, cm));
            const float e7 = __builtin_amdgcn_exp2f(fmaf(Q[3], CSC, cm));
            s[rt] += ((e0 + e1) + (e2 + e3)) + ((e4 + e5) + (e6 + e7));
        }
        buf ^= 1;
    }

    // per-wave row-reduce: lanes sharing a row differ only in lg (xor 16,32)
#pragma unroll
    for (int rt = 0; rt < 4; ++rt) {
        float M = m[rt];
        M = fmaxf(M, __shfl_xor(M, 16, 64));
        M = fmaxf(M, __shfl_xor(M, 32, 64));
        float sc = s[rt] * __builtin_amdgcn_exp2f(fmaf(m[rt], CSC, M * NCSC));
        sc += __shfl_xor(sc, 16, 64);
        sc += __shfl_xor(sc, 32, 64);
        if (lg == 0) {
            const int row = (RT0 + rt) * 16 + lr;
            pm[blockIdx.y * N_TOT + row] = M;
            ps[blockIdx.y * N_TOT + row] = sc;
        }
    }
}

// ---------- kernel 3: merge partials + fp32 positive dot + mean (32 blocks) ----------
__global__ __launch_bounds__(256)
void rowloss_mean_kernel(const float* __restrict__ pm, const float* __restrict__ ps,
                         const float* __restrict__ feat, float* __restrict__ out) {
    const int row = blockIdx.x * 256 + threadIdx.x;
    float M = pm[row], S = ps[row];
#pragma unroll
    for (int c = 1; c < CS; ++c) {
        const float Mo = pm[c * N_TOT + row], So = ps[c * N_TOT + row];
        const float mn = fmaxf(M, Mo);
        S = fmaf(S,  __builtin_amdgcn_exp2f(fmaf(M,  CSC, mn * NCSC)),
                 So * __builtin_amdgcn_exp2f(fmaf(Mo, CSC, mn * NCSC)));
        M = mn;
    }
    // positive in fp32 straight from the original features
    const float4* f = reinterpret_cast<const float4*>(feat + (size_t)row * D);
    const float4* g = reinterpret_cast<const float4*>(feat + (size_t)(row ^ HALF_N) * D);
    float dot = 0.f;
#pragma unroll
    for (int j = 0; j < 32; ++j) {
        const float4 a = f[j], b = g[j];
        dot += a.x * b.x + a.y * b.y + a.z * b.z + a.w * b.w;
    }
    float acc = LN2F * fmaf(M, CSC, __builtin_amdgcn_logf(S)) - dot * INV_T;
#pragma unroll
    for (int off = 32; off > 0; off >>= 1) acc += __shfl_xor(acc, off, 64);
    __shared__ float ls[4];
    if ((threadIdx.x & 63) == 0) ls[threadIdx.x >> 6] = acc;
    __syncthreads();
    if (threadIdx.x == 0)
        atomicAdd(out, (ls[0] + ls[1] + ls[2] + ls[3]) * (1.0f / (float)N_TOT));
}

extern "C" void kernel_launch(void* const* d_in, const int* in_sizes, int n_in,
                              void* d_out, int out_size, void* d_ws, size_t ws_size,
                              hipStream_t stream) {
    const float* feat = (const float*)d_in[0];
    char* ws = (char*)d_ws;
    unsigned short* fbP = (unsigned short*)ws;                                  // 2 MB
    float* pm      = (float*)(ws + (size_t)N_TOT * D * 2);                      // 512 KB
    float* ps      = (float*)(ws + (size_t)N_TOT * D * 2 + (size_t)CS * N_TOT * 4);       // 512 KB
    float* out = (float*)d_out;

    cvt_kernel<<<512, 256, 0, stream>>>(feat, fbP, out);
    simclr_kernel<<<dim3(32, CS), 256, 0, stream>>>(fbP, pm, ps);
    rowloss_mean_kernel<<<N_TOT / 256, 256, 0, stream>>>(pm, ps, feat, out);
}

// Round 17
// 42.377 us; speedup vs baseline: 1.1272x; 1.0742x over previous
//
#include <hip/hip_runtime.h>
#include <math.h>

typedef __bf16 bf16x8 __attribute__((ext_vector_type(8)));
typedef float f32x4 __attribute__((ext_vector_type(4)));
typedef unsigned short u16x8 __attribute__((ext_vector_type(8)));

#define N_TOT 8192
#define HALF_N 4096
#define D 128
#define INV_T 14.285714285714286f
#define CSC 20.609929155556627f    /* (1/0.07) * log2(e) */
#define NCSC -20.609929155556627f
#define LN2F 0.69314718055994531f
#define NEG_BIG -3.0e38f
#define M_INIT -1.0e30f
#define THR_RAW 1.0f                /* defer-max slack (raw units) */
#define CS 16                       /* col groups of 512 = 32 tiles */

__device__ __forceinline__ unsigned short f2bf(float f) {
    union { float f; unsigned int u; } a; a.f = f;
    unsigned int u = a.u;
    return (unsigned short)((u + 0x7fffu + ((u >> 16) & 1u)) >> 16);
}

// ---------- kernel 1: fp32 -> bf16 packed in MFMA-fragment order ----------
// fbP chunk c (16B): c = (T*4 + kk)*64 + lg*16 + lr  holds
// F[col = T*16 + lr][kk*32 + lg*8 .. +8]; a (tile,kk) wave-load is one
// contiguous 1KB read; 4 consecutive tiles are a contiguous 16 KB span.
// Thread (0,0) zero-inits the output accumulator (replaces memset node).
__global__ __launch_bounds__(256)
void cvt_kernel(const float* __restrict__ in, unsigned short* __restrict__ fbP,
                float* __restrict__ out) {
    if (blockIdx.x == 0 && threadIdx.x == 0) out[0] = 0.f;
    const int c   = blockIdx.x * 256 + threadIdx.x;
    const int q   = c >> 6;
    const int rem = c & 63;
    const int lg  = rem >> 4, lr = rem & 15;
    const int kk  = q & 3;
    const int col = (q >> 2) * 16 + lr;
    const int j16 = kk * 4 + lg;
    const float4 v0 = reinterpret_cast<const float4*>(in)[col * 32 + j16 * 2];
    const float4 v1 = reinterpret_cast<const float4*>(in)[col * 32 + j16 * 2 + 1];
    u16x8 o;
    o[0] = f2bf(v0.x); o[1] = f2bf(v0.y); o[2] = f2bf(v0.z); o[3] = f2bf(v0.w);
    o[4] = f2bf(v1.x); o[5] = f2bf(v1.y); o[6] = f2bf(v1.z); o[7] = f2bf(v1.w);
    reinterpret_cast<u16x8*>(fbP)[c] = o;
}

// ---------- kernel 2: fused sim + online logsumexp, 16KB staging phases ----------
// R14 structure verbatim (best measured): grid (32 rowgroups, 16 colgroups),
// 256 thr = 4 waves, 3 blocks/CU. Wave w HOLDS rows [rg*256 + w*64, +64).
// Block stages 16 KB (4 col-tiles) per phase via global_load_lds (linear both
// sides), double-buffered, one __syncthreads per phase (8 per col-group).
// Positives handled entirely in kernel 3 -> no stores in the hot loop.
__global__ __launch_bounds__(256, 3)
void simclr_kernel(const unsigned short* __restrict__ fbP,
                   float* __restrict__ pm, float* __restrict__ ps) {
    __shared__ __align__(16) unsigned short lds[2][8192];   // 2 x 16 KB
    const int tid  = threadIdx.x;
    const int lane = tid & 63;
    const int wid  = tid >> 6;              // 0..3
    const int lr   = lane & 15;
    const int lg   = lane >> 4;
    const int RT0  = blockIdx.x * 16 + wid * 4;   // first held row-tile
    const int Tw   = blockIdx.y * 32;             // first streamed col-tile

    // held rows: 4 row-tiles (distinct per wave), loaded once from L2
    bf16x8 br[4][4];
#pragma unroll
    for (int rt = 0; rt < 4; ++rt)
#pragma unroll
        for (int kk = 0; kk < 4; ++kk)
            br[rt][kk] = *reinterpret_cast<const bf16x8*>(
                fbP + ((size_t)(((RT0 + rt) * 4 + kk) * 64) + lane) * 8);

    float m[4], s[4];
#pragma unroll
    for (int rt = 0; rt < 4; ++rt) { m[rt] = M_INIT; s[rt] = 0.f; }

    // stage phase q's 16 KB (tiles Tw+4q .. +3) -> lds[b]: linear both sides
    auto stage = [&](int q, int b) {
#pragma unroll
        for (int h = 0; h < 4; ++h) {
            const unsigned short* src =
                fbP + ((size_t)(Tw + 4 * q + h) * 256 + tid) * 8;
            unsigned short* dst = &lds[b][(h * 256 + tid) * 8];
            __builtin_amdgcn_global_load_lds(
                (const __attribute__((address_space(1))) unsigned int*)(const void*)src,
                (__attribute__((address_space(3))) unsigned int*)(void*)dst,
                16, 0, 0);
        }
    };

    stage(0, 0);
    __syncthreads();

    int buf = 0;
#pragma unroll 1
    for (int q = 0; q < 8; ++q) {
        if (q < 7) stage(q + 1, buf ^ 1);   // 16 KB lands under 2 pair-computations

#pragma unroll
        for (int pp = 0; pp < 2; ++pp) {
            const unsigned short* B = &lds[buf][pp * 4096];
            bf16x8 ca[4], cb[4];
#pragma unroll
            for (int kk = 0; kk < 4; ++kk) {
                ca[kk] = *reinterpret_cast<const bf16x8*>(&B[(kk * 64 + lane) * 8]);
                cb[kk] = *reinterpret_cast<const bf16x8*>(&B[((kk + 4) * 64 + lane) * 8]);
            }

            const int c0 = blockIdx.y * 512 + (q * 4 + pp * 2) * 16;  // [c0, c0+32)

            f32x4 accP[4], accQ[4];
#pragma unroll
            for (int rt = 0; rt < 4; ++rt) accP[rt] = f32x4{0.f, 0.f, 0.f, 0.f};
#pragma unroll
            for (int kk = 0; kk < 4; ++kk)
#pragma unroll
                for (int rt = 0; rt < 4; ++rt)
                    accP[rt] = __builtin_amdgcn_mfma_f32_16x16x32_bf16(ca[kk], br[rt][kk], accP[rt], 0, 0, 0);
#pragma unroll
            for (int rt = 0; rt < 4; ++rt) accQ[rt] = f32x4{0.f, 0.f, 0.f, 0.f};
#pragma unroll
            for (int kk = 0; kk < 4; ++kk)
#pragma unroll
                for (int rt = 0; rt < 4; ++rt)
                    accQ[rt] = __builtin_amdgcn_mfma_f32_16x16x32_bf16(cb[kk], br[rt][kk], accQ[rt], 0, 0, 0);

            // merged pair epilogue: lane's elems = sim[rowbase+lr][c0 + lg*4+r (+16)]
#pragma unroll
            for (int rt = 0; rt < 4; ++rt) {
                const int rowbase = (RT0 + rt) * 16;
                f32x4 P = accP[rt], Q = accQ[rt];
                if (c0 == rowbase) {                  // wave-uniform: diagonal tile
#pragma unroll
                    for (int r = 0; r < 4; ++r)
                        if (lr == lg * 4 + r) P[r] = NEG_BIG;
                }
                if (c0 + 16 == rowbase) {
#pragma unroll
                    for (int r = 0; r < 4; ++r)
                        if (lr == lg * 4 + r) Q[r] = NEG_BIG;
                }
                const float t1 = fmaxf(fmaxf(P[0], P[1]), P[2]);
                const float t2 = fmaxf(fmaxf(P[3], Q[0]), Q[1]);
                const float t3 = fmaxf(Q[2], Q[3]);
                const float rmax = fmaxf(fmaxf(t1, t2), t3);
                // defer-max: rescale only when some lane exceeds m+THR
                if (!__all(rmax <= m[rt] + THR_RAW)) {
                    const float mn = fmaxf(m[rt], rmax);
                    s[rt] *= __builtin_amdgcn_exp2f(fmaf(m[rt], CSC, mn * NCSC));
                    m[rt] = mn;
                }
                const float cm = m[rt] * NCSC;
                const float e0 = __builtin_amdgcn_exp2f(fmaf(P[0], CSC, cm));
                const float e1 = __builtin_amdgcn_exp2f(fmaf(P[1], CSC, cm));
                const float e2 = __builtin_amdgcn_exp2f(fmaf(P[2], CSC, cm));
                const float e3 = __builtin_amdgcn_exp2f(fmaf(P[3], CSC, cm));
                const float e4 = __builtin_amdgcn_exp2f(fmaf(Q[0], CSC, cm));
                const float e5 = __builtin_amdgcn_exp2f(fmaf(Q[1], CSC, cm));
                const float e6 = __builtin_amdgcn_exp2f(fmaf(Q[2], CSC, cm));
                const float e7 = __builtin_amdgcn_exp2f(fmaf(Q[3], CSC, cm));
                s[rt] += ((e0 + e1) + (e2 + e3)) + ((e4 + e5) + (e6 + e7));
            }
        }

        __syncthreads();    // vmcnt(0)+barrier: next 16KB staged & reads done
        buf ^= 1;
    }

    // per-wave row-reduce: lanes sharing a row differ only in lg (xor 16,32)
#pragma unroll
    for (int rt = 0; rt < 4; ++rt) {
        float M = m[rt];
        M = fmaxf(M, __shfl_xor(M, 16, 64));
        M = fmaxf(M, __shfl_xor(M, 32, 64));
        float sc = s[rt] * __builtin_amdgcn_exp2f(fmaf(m[rt], CSC, M * NCSC));
        sc += __shfl_xor(sc, 16, 64);
        sc += __shfl_xor(sc, 32, 64);
        if (lg == 0) {
            const int row = (RT0 + rt) * 16 + lr;
            pm[blockIdx.y * N_TOT + row] = M;
            ps[blockIdx.y * N_TOT + row] = sc;
        }
    }
}

// ---------- kernel 3: merge partials + fp32 positive dot + mean (32 blocks) ----------
__global__ __launch_bounds__(256)
void rowloss_mean_kernel(const float* __restrict__ pm, const float* __restrict__ ps,
                         const float* __restrict__ feat, float* __restrict__ out) {
    const int row = blockIdx.x * 256 + threadIdx.x;
    float M = pm[row], S = ps[row];
#pragma unroll
    for (int c = 1; c < CS; ++c) {
        const float Mo = pm[c * N_TOT + row], So = ps[c * N_TOT + row];
        const float mn = fmaxf(M, Mo);
        S = fmaf(S,  __builtin_amdgcn_exp2f(fmaf(M,  CSC, mn * NCSC)),
                 So * __builtin_amdgcn_exp2f(fmaf(Mo, CSC, mn * NCSC)));
        M = mn;
    }
    // positive in fp32 straight from the original features
    const float4* f = reinterpret_cast<const float4*>(feat + (size_t)row * D);
    const float4* g = reinterpret_cast<const float4*>(feat + (size_t)(row ^ HALF_N) * D);
    float dot = 0.f;
#pragma unroll
    for (int j = 0; j < 32; ++j) {
        const float4 a = f[j], b = g[j];
        dot += a.x * b.x + a.y * b.y + a.z * b.z + a.w * b.w;
    }
    float acc = LN2F * fmaf(M, CSC, __builtin_amdgcn_logf(S)) - dot * INV_T;
#pragma unroll
    for (int off = 32; off > 0; off >>= 1) acc += __shfl_xor(acc, off, 64);
    __shared__ float ls[4];
    if ((threadIdx.x & 63) == 0) ls[threadIdx.x >> 6] = acc;
    __syncthreads();
    if (threadIdx.x == 0)
        atomicAdd(out, (ls[0] + ls[1] + ls[2] + ls[3]) * (1.0f / (float)N_TOT));
}

extern "C" void kernel_launch(void* const* d_in, const int* in_sizes, int n_in,
                              void* d_out, int out_size, void* d_ws, size_t ws_size,
                              hipStream_t stream) {
    const float* feat = (const float*)d_in[0];
    char* ws = (char*)d_ws;
    unsigned short* fbP = (unsigned short*)ws;                                  // 2 MB
    float* pm      = (float*)(ws + (size_t)N_TOT * D * 2);                      // 512 KB
    float* ps      = (float*)(ws + (size_t)N_TOT * D * 2 + (size_t)CS * N_TOT * 4);       // 512 KB
    float* out = (float*)d_out;

    cvt_kernel<<<512, 256, 0, stream>>>(feat, fbP, out);
    simclr_kernel<<<dim3(32, CS), 256, 0, stream>>>(fbP, pm, ps);
    rowloss_mean_kernel<<<N_TOT / 256, 256, 0, stream>>>(pm, ps, feat, out);
}

// Round 18
// 36.959 us; speedup vs baseline: 1.2924x; 1.1466x over previous
//
#include <hip/hip_runtime.h>
#include <math.h>

typedef __bf16 bf16x8 __attribute__((ext_vector_type(8)));
typedef float f32x4 __attribute__((ext_vector_type(4)));
typedef unsigned short u16x8 __attribute__((ext_vector_type(8)));

#define N_TOT 8192
#define HALF_N 4096
#define D 128
#define INV_T 14.285714285714286f
#define CSC 20.609929155556627f    /* (1/0.07) * log2(e) */
#define NCSC -20.609929155556627f
#define LN2F 0.69314718055994531f
#define NEG_BIG -3.0e38f
#define M_INIT -1.0e30f
#define THR_RAW 1.0f                /* defer-max slack (raw units) */
#define CS 16                       /* col groups of 512 = 32 tiles */

__device__ __forceinline__ unsigned short f2bf(float f) {
    union { float f; unsigned int u; } a; a.f = f;
    unsigned int u = a.u;
    return (unsigned short)((u + 0x7fffu + ((u >> 16) & 1u)) >> 16);
}

// ---------- kernel 1: fp32 -> bf16 packed in MFMA-fragment order ----------
// fbP chunk c (16B): c = (T*4 + kk)*64 + lg*16 + lr  holds
// F[col = T*16 + lr][kk*32 + lg*8 .. +8]; a (tile,kk) wave-load is one
// contiguous 1KB read; 4 consecutive tiles are a contiguous 16 KB span.
// Thread (0,0) zero-inits the output accumulator (replaces memset node).
__global__ __launch_bounds__(256)
void cvt_kernel(const float* __restrict__ in, unsigned short* __restrict__ fbP,
                float* __restrict__ out) {
    if (blockIdx.x == 0 && threadIdx.x == 0) out[0] = 0.f;
    const int c   = blockIdx.x * 256 + threadIdx.x;
    const int q   = c >> 6;
    const int rem = c & 63;
    const int lg  = rem >> 4, lr = rem & 15;
    const int kk  = q & 3;
    const int col = (q >> 2) * 16 + lr;
    const int j16 = kk * 4 + lg;
    const float4 v0 = reinterpret_cast<const float4*>(in)[col * 32 + j16 * 2];
    const float4 v1 = reinterpret_cast<const float4*>(in)[col * 32 + j16 * 2 + 1];
    u16x8 o;
    o[0] = f2bf(v0.x); o[1] = f2bf(v0.y); o[2] = f2bf(v0.z); o[3] = f2bf(v0.w);
    o[4] = f2bf(v1.x); o[5] = f2bf(v1.y); o[6] = f2bf(v1.z); o[7] = f2bf(v1.w);
    reinterpret_cast<u16x8*>(fbP)[c] = o;
}

// ---------- kernel 2: fused sim + online logsumexp, 16KB staging phases ----------
// R14 structure verbatim (best measured, 40.5 us): grid (32 rowgroups, 16
// colgroups), 256 thr = 4 waves, 3 blocks/CU. Wave w HOLDS rows
// [rg*256 + w*64, +64) (4 row-tiles). Block stages 16 KB (4 col-tiles) per
// phase via global_load_lds (linear both sides), double-buffered; one
// __syncthreads per phase (8 per col-group — the measured sweet spot:
// 32/16/8 drains -> 49.9/42.8/40.5). Positives harvested in-loop (rowpos).
__global__ __launch_bounds__(256, 3)
void simclr_kernel(const unsigned short* __restrict__ fbP,
                   float* __restrict__ pm, float* __restrict__ ps,
                   float* __restrict__ rowpos) {
    __shared__ __align__(16) unsigned short lds[2][8192];   // 2 x 16 KB
    const int tid  = threadIdx.x;
    const int lane = tid & 63;
    const int wid  = tid >> 6;              // 0..3
    const int lr   = lane & 15;
    const int lg   = lane >> 4;
    const int RT0  = blockIdx.x * 16 + wid * 4;   // first held row-tile
    const int Tw   = blockIdx.y * 32;             // first streamed col-tile

    // held rows: 4 row-tiles (distinct per wave), loaded once from L2
    bf16x8 br[4][4];
#pragma unroll
    for (int rt = 0; rt < 4; ++rt)
#pragma unroll
        for (int kk = 0; kk < 4; ++kk)
            br[rt][kk] = *reinterpret_cast<const bf16x8*>(
                fbP + ((size_t)(((RT0 + rt) * 4 + kk) * 64) + lane) * 8);

    float m[4], s[4];
#pragma unroll
    for (int rt = 0; rt < 4; ++rt) { m[rt] = M_INIT; s[rt] = 0.f; }

    // stage phase q's 16 KB (tiles Tw+4q .. +3) -> lds[b]: linear both sides
    auto stage = [&](int q, int b) {
#pragma unroll
        for (int h = 0; h < 4; ++h) {
            const unsigned short* src =
                fbP + ((size_t)(Tw + 4 * q + h) * 256 + tid) * 8;
            unsigned short* dst = &lds[b][(h * 256 + tid) * 8];
            __builtin_amdgcn_global_load_lds(
                (const __attribute__((address_space(1))) unsigned int*)(const void*)src,
                (__attribute__((address_space(3))) unsigned int*)(void*)dst,
                16, 0, 0);
        }
    };

    stage(0, 0);
    __syncthreads();

    int buf = 0;
#pragma unroll 1
    for (int q = 0; q < 8; ++q) {
        if (q < 7) stage(q + 1, buf ^ 1);   // 16 KB lands under 2 pair-computations

#pragma unroll
        for (int pp = 0; pp < 2; ++pp) {
            const unsigned short* B = &lds[buf][pp * 4096];
            bf16x8 ca[4], cb[4];
#pragma unroll
            for (int kk = 0; kk < 4; ++kk) {
                ca[kk] = *reinterpret_cast<const bf16x8*>(&B[(kk * 64 + lane) * 8]);
                cb[kk] = *reinterpret_cast<const bf16x8*>(&B[((kk + 4) * 64 + lane) * 8]);
            }

            const int c0 = blockIdx.y * 512 + (q * 4 + pp * 2) * 16;  // [c0, c0+32)

            f32x4 accP[4], accQ[4];
#pragma unroll
            for (int rt = 0; rt < 4; ++rt) accP[rt] = f32x4{0.f, 0.f, 0.f, 0.f};
#pragma unroll
            for (int kk = 0; kk < 4; ++kk)
#pragma unroll
                for (int rt = 0; rt < 4; ++rt)
                    accP[rt] = __builtin_amdgcn_mfma_f32_16x16x32_bf16(ca[kk], br[rt][kk], accP[rt], 0, 0, 0);
#pragma unroll
            for (int rt = 0; rt < 4; ++rt) accQ[rt] = f32x4{0.f, 0.f, 0.f, 0.f};
#pragma unroll
            for (int kk = 0; kk < 4; ++kk)
#pragma unroll
                for (int rt = 0; rt < 4; ++rt)
                    accQ[rt] = __builtin_amdgcn_mfma_f32_16x16x32_bf16(cb[kk], br[rt][kk], accQ[rt], 0, 0, 0);

            // merged pair epilogue: lane's elems = sim[rowbase+lr][c0 + lg*4+r (+16)]
#pragma unroll
            for (int rt = 0; rt < 4; ++rt) {
                const int rowbase = (RT0 + rt) * 16;
                f32x4 P = accP[rt], Q = accQ[rt];
                if (c0 == (rowbase ^ HALF_N)) {       // wave-uniform: positive tile
#pragma unroll
                    for (int r = 0; r < 4; ++r)
                        if (lr == lg * 4 + r) rowpos[rowbase + lr] = P[r];
                }
                if (c0 + 16 == (rowbase ^ HALF_N)) {
#pragma unroll
                    for (int r = 0; r < 4; ++r)
                        if (lr == lg * 4 + r) rowpos[rowbase + lr] = Q[r];
                }
                if (c0 == rowbase) {                  // wave-uniform: diagonal tile
#pragma unroll
                    for (int r = 0; r < 4; ++r)
                        if (lr == lg * 4 + r) P[r] = NEG_BIG;
                }
                if (c0 + 16 == rowbase) {
#pragma unroll
                    for (int r = 0; r < 4; ++r)
                        if (lr == lg * 4 + r) Q[r] = NEG_BIG;
                }
                const float t1 = fmaxf(fmaxf(P[0], P[1]), P[2]);
                const float t2 = fmaxf(fmaxf(P[3], Q[0]), Q[1]);
                const float t3 = fmaxf(Q[2], Q[3]);
                const float rmax = fmaxf(fmaxf(t1, t2), t3);
                // defer-max: rescale only when some lane exceeds m+THR
                if (!__all(rmax <= m[rt] + THR_RAW)) {
                    const float mn = fmaxf(m[rt], rmax);
                    s[rt] *= __builtin_amdgcn_exp2f(fmaf(m[rt], CSC, mn * NCSC));
                    m[rt] = mn;
                }
                const float cm = m[rt] * NCSC;
                const float e0 = __builtin_amdgcn_exp2f(fmaf(P[0], CSC, cm));
                const float e1 = __builtin_amdgcn_exp2f(fmaf(P[1], CSC, cm));
                const float e2 = __builtin_amdgcn_exp2f(fmaf(P[2], CSC, cm));
                const float e3 = __builtin_amdgcn_exp2f(fmaf(P[3], CSC, cm));
                const float e4 = __builtin_amdgcn_exp2f(fmaf(Q[0], CSC, cm));
                const float e5 = __builtin_amdgcn_exp2f(fmaf(Q[1], CSC, cm));
                const float e6 = __builtin_amdgcn_exp2f(fmaf(Q[2], CSC, cm));
                const float e7 = __builtin_amdgcn_exp2f(fmaf(Q[3], CSC, cm));
                s[rt] += ((e0 + e1) + (e2 + e3)) + ((e4 + e5) + (e6 + e7));
            }
        }

        __syncthreads();    // vmcnt(0)+barrier: next 16KB staged & reads done
        buf ^= 1;
    }

    // per-wave row-reduce: lanes sharing a row differ only in lg (xor 16,32)
#pragma unroll
    for (int rt = 0; rt < 4; ++rt) {
        float M = m[rt];
        M = fmaxf(M, __shfl_xor(M, 16, 64));
        M = fmaxf(M, __shfl_xor(M, 32, 64));
        float sc = s[rt] * __builtin_amdgcn_exp2f(fmaf(m[rt], CSC, M * NCSC));
        sc += __shfl_xor(sc, 16, 64);
        sc += __shfl_xor(sc, 32, 64);
        if (lg == 0) {
            const int row = (RT0 + rt) * 16 + lr;
            pm[blockIdx.y * N_TOT + row] = M;
            ps[blockIdx.y * N_TOT + row] = sc;
        }
    }
}

// ---------- kernel 3: merge col-group partials, row loss, mean (32 blocks) ----------
__global__ __launch_bounds__(256)
void rowloss_mean_kernel(const float* __restrict__ pm, const float* __restrict__ ps,
                         const float* __restrict__ rowpos, float* __restrict__ out) {
    const int row = blockIdx.x * 256 + threadIdx.x;
    float M = pm[row], S = ps[row];
#pragma unroll
    for (int c = 1; c < CS; ++c) {
        const float Mo = pm[c * N_TOT + row], So = ps[c * N_TOT + row];
        const float mn = fmaxf(M, Mo);
        S = fmaf(S,  __builtin_amdgcn_exp2f(fmaf(M,  CSC, mn * NCSC)),
                 So * __builtin_amdgcn_exp2f(fmaf(Mo, CSC, mn * NCSC)));
        M = mn;
    }
    float acc = LN2F * fmaf(M, CSC, __builtin_amdgcn_logf(S)) - rowpos[row] * INV_T;
#pragma unroll
    for (int off = 32; off > 0; off >>= 1) acc += __shfl_xor(acc, off, 64);
    __shared__ float ls[4];
    if ((threadIdx.x & 63) == 0) ls[threadIdx.x >> 6] = acc;
    __syncthreads();
    if (threadIdx.x == 0)
        atomicAdd(out, (ls[0] + ls[1] + ls[2] + ls[3]) * (1.0f / (float)N_TOT));
}

extern "C" void kernel_launch(void* const* d_in, const int* in_sizes, int n_in,
                              void* d_out, int out_size, void* d_ws, size_t ws_size,
                              hipStream_t stream) {
    const float* feat = (const float*)d_in[0];
    char* ws = (char*)d_ws;
    unsigned short* fbP = (unsigned short*)ws;                                  // 2 MB
    float* pm      = (float*)(ws + (size_t)N_TOT * D * 2);                      // 512 KB
    float* ps      = (float*)(ws + (size_t)N_TOT * D * 2 + (size_t)CS * N_TOT * 4);       // 512 KB
    float* rowpos  = (float*)(ws + (size_t)N_TOT * D * 2 + 2 * (size_t)CS * N_TOT * 4);   // 32 KB
    float* out = (float*)d_out;

    cvt_kernel<<<512, 256, 0, stream>>>(feat, fbP, out);
    simclr_kernel<<<dim3(32, CS), 256, 0, stream>>>(fbP, pm, ps, rowpos);
    rowloss_mean_kernel<<<N_TOT / 256, 256, 0, stream>>>(pm, ps, rowpos, out);
}

// Round 19
// 36.761 us; speedup vs baseline: 1.2994x; 1.0054x over previous
//
#include <hip/hip_runtime.h>
#include <math.h>

typedef __bf16 bf16x8 __attribute__((ext_vector_type(8)));
typedef float f32x4 __attribute__((ext_vector_type(4)));
typedef unsigned short u16x8 __attribute__((ext_vector_type(8)));

#define N_TOT 8192
#define HALF_N 4096
#define D 128
#define INV_T 14.285714285714286f
#define CSC 20.609929155556627f    /* (1/0.07) * log2(e) */
#define NCSC -20.609929155556627f
#define LN2F 0.69314718055994531f
#define NEG_BIG -3.0e38f
#define M_INIT -1.0e30f
#define THR_RAW 1.0f                /* defer-max slack (raw units) */
#define CS 16                       /* col groups of 512 = 32 tiles */

__device__ __forceinline__ unsigned short f2bf(float f) {
    union { float f; unsigned int u; } a; a.f = f;
    unsigned int u = a.u;
    return (unsigned short)((u + 0x7fffu + ((u >> 16) & 1u)) >> 16);
}

// ---------- kernel 1: fp32 -> bf16 packed in MFMA-fragment order ----------
// fbP chunk c (16B): c = (T*4 + kk)*64 + lg*16 + lr  holds
// F[col = T*16 + lr][kk*32 + lg*8 .. +8]; a (tile,kk) wave-load is one
// contiguous 1KB read; 8 consecutive tiles are a contiguous 32 KB span.
// Thread (0,0) zero-inits the output accumulator (replaces memset node).
__global__ __launch_bounds__(256)
void cvt_kernel(const float* __restrict__ in, unsigned short* __restrict__ fbP,
                float* __restrict__ out) {
    if (blockIdx.x == 0 && threadIdx.x == 0) out[0] = 0.f;
    const int c   = blockIdx.x * 256 + threadIdx.x;
    const int q   = c >> 6;
    const int rem = c & 63;
    const int lg  = rem >> 4, lr = rem & 15;
    const int kk  = q & 3;
    const int col = (q >> 2) * 16 + lr;
    const int j16 = kk * 4 + lg;
    const float4 v0 = reinterpret_cast<const float4*>(in)[col * 32 + j16 * 2];
    const float4 v1 = reinterpret_cast<const float4*>(in)[col * 32 + j16 * 2 + 1];
    u16x8 o;
    o[0] = f2bf(v0.x); o[1] = f2bf(v0.y); o[2] = f2bf(v0.z); o[3] = f2bf(v0.w);
    o[4] = f2bf(v1.x); o[5] = f2bf(v1.y); o[6] = f2bf(v1.z); o[7] = f2bf(v1.w);
    reinterpret_cast<u16x8*>(fbP)[c] = o;
}

// ---------- kernel 2: fused sim + online logsumexp, 32KB staging phases ----------
// R18 structure with the barrier ladder extended one step (8 -> 4 loop
// barriers): grid (32 rowgroups, 16 colgroups), 256 thr = 4 waves, 2 blocks/CU
// (64 KB LDS). Wave w HOLDS rows [rg*256 + w*64, +64). Block stages 32 KB
// (8 col-tiles) per phase via global_load_lds (linear both sides),
// double-buffered; one __syncthreads per phase. 4 pairs per phase.
__global__ __launch_bounds__(256, 2)
void simclr_kernel(const unsigned short* __restrict__ fbP,
                   float* __restrict__ pm, float* __restrict__ ps,
                   float* __restrict__ rowpos) {
    __shared__ __align__(16) unsigned short lds[2][16384];   // 2 x 32 KB
    const int tid  = threadIdx.x;
    const int lane = tid & 63;
    const int wid  = tid >> 6;              // 0..3
    const int lr   = lane & 15;
    const int lg   = lane >> 4;
    const int RT0  = blockIdx.x * 16 + wid * 4;   // first held row-tile
    const int Tw   = blockIdx.y * 32;             // first streamed col-tile

    // held rows: 4 row-tiles (distinct per wave), loaded once from L2
    bf16x8 br[4][4];
#pragma unroll
    for (int rt = 0; rt < 4; ++rt)
#pragma unroll
        for (int kk = 0; kk < 4; ++kk)
            br[rt][kk] = *reinterpret_cast<const bf16x8*>(
                fbP + ((size_t)(((RT0 + rt) * 4 + kk) * 64) + lane) * 8);

    float m[4], s[4];
#pragma unroll
    for (int rt = 0; rt < 4; ++rt) { m[rt] = M_INIT; s[rt] = 0.f; }

    // stage phase q's 32 KB (tiles Tw+8q .. +7) -> lds[b]: linear both sides
    auto stage = [&](int q, int b) {
#pragma unroll
        for (int h = 0; h < 8; ++h) {
            const unsigned short* src =
                fbP + ((size_t)(Tw + 8 * q) * 256 + h * 256 + tid) * 8;
            unsigned short* dst = &lds[b][(h * 256 + tid) * 8];
            __builtin_amdgcn_global_load_lds(
                (const __attribute__((address_space(1))) unsigned int*)(const void*)src,
                (__attribute__((address_space(3))) unsigned int*)(void*)dst,
                16, 0, 0);
        }
    };

    stage(0, 0);
    __syncthreads();

    int buf = 0;
#pragma unroll 1
    for (int q = 0; q < 4; ++q) {
        if (q < 3) stage(q + 1, buf ^ 1);   // 32 KB lands under 4 pair-computations

#pragma unroll
        for (int pp = 0; pp < 4; ++pp) {
            const unsigned short* B = &lds[buf][pp * 4096];
            bf16x8 ca[4], cb[4];
#pragma unroll
            for (int kk = 0; kk < 4; ++kk) {
                ca[kk] = *reinterpret_cast<const bf16x8*>(&B[(kk * 64 + lane) * 8]);
                cb[kk] = *reinterpret_cast<const bf16x8*>(&B[((kk + 4) * 64 + lane) * 8]);
            }

            const int c0 = blockIdx.y * 512 + (q * 8 + pp * 2) * 16;  // [c0, c0+32)

            f32x4 accP[4], accQ[4];
#pragma unroll
            for (int rt = 0; rt < 4; ++rt) accP[rt] = f32x4{0.f, 0.f, 0.f, 0.f};
#pragma unroll
            for (int kk = 0; kk < 4; ++kk)
#pragma unroll
                for (int rt = 0; rt < 4; ++rt)
                    accP[rt] = __builtin_amdgcn_mfma_f32_16x16x32_bf16(ca[kk], br[rt][kk], accP[rt], 0, 0, 0);
#pragma unroll
            for (int rt = 0; rt < 4; ++rt) accQ[rt] = f32x4{0.f, 0.f, 0.f, 0.f};
#pragma unroll
            for (int kk = 0; kk < 4; ++kk)
#pragma unroll
                for (int rt = 0; rt < 4; ++rt)
                    accQ[rt] = __builtin_amdgcn_mfma_f32_16x16x32_bf16(cb[kk], br[rt][kk], accQ[rt], 0, 0, 0);

            // merged pair epilogue: lane's elems = sim[rowbase+lr][c0 + lg*4+r (+16)]
#pragma unroll
            for (int rt = 0; rt < 4; ++rt) {
                const int rowbase = (RT0 + rt) * 16;
                f32x4 P = accP[rt], Q = accQ[rt];
                if (c0 == (rowbase ^ HALF_N)) {       // wave-uniform: positive tile
#pragma unroll
                    for (int r = 0; r < 4; ++r)
                        if (lr == lg * 4 + r) rowpos[rowbase + lr] = P[r];
                }
                if (c0 + 16 == (rowbase ^ HALF_N)) {
#pragma unroll
                    for (int r = 0; r < 4; ++r)
                        if (lr == lg * 4 + r) rowpos[rowbase + lr] = Q[r];
                }
                if (c0 == rowbase) {                  // wave-uniform: diagonal tile
#pragma unroll
                    for (int r = 0; r < 4; ++r)
                        if (lr == lg * 4 + r) P[r] = NEG_BIG;
                }
                if (c0 + 16 == rowbase) {
#pragma unroll
                    for (int r = 0; r < 4; ++r)
                        if (lr == lg * 4 + r) Q[r] = NEG_BIG;
                }
                const float t1 = fmaxf(fmaxf(P[0], P[1]), P[2]);
                const float t2 = fmaxf(fmaxf(P[3], Q[0]), Q[1]);
                const float t3 = fmaxf(Q[2], Q[3]);
                const float rmax = fmaxf(fmaxf(t1, t2), t3);
                // defer-max: rescale only when some lane exceeds m+THR
                if (!__all(rmax <= m[rt] + THR_RAW)) {
                    const float mn = fmaxf(m[rt], rmax);
                    s[rt] *= __builtin_amdgcn_exp2f(fmaf(m[rt], CSC, mn * NCSC));
                    m[rt] = mn;
                }
                const float cm = m[rt] * NCSC;
                const float e0 = __builtin_amdgcn_exp2f(fmaf(P[0], CSC, cm));
                const float e1 = __builtin_amdgcn_exp2f(fmaf(P[1], CSC, cm));
                const float e2 = __builtin_amdgcn_exp2f(fmaf(P[2], CSC, cm));
                const float e3 = __builtin_amdgcn_exp2f(fmaf(P[3], CSC, cm));
                const float e4 = __builtin_amdgcn_exp2f(fmaf(Q[0], CSC, cm));
                const float e5 = __builtin_amdgcn_exp2f(fmaf(Q[1], CSC, cm));
                const float e6 = __builtin_amdgcn_exp2f(fmaf(Q[2], CSC, cm));
                const float e7 = __builtin_amdgcn_exp2f(fmaf(Q[3], CSC, cm));
                s[rt] += ((e0 + e1) + (e2 + e3)) + ((e4 + e5) + (e6 + e7));
            }
        }

        __syncthreads();    // vmcnt(0)+barrier: next 32KB staged & reads done
        buf ^= 1;
    }

    // per-wave row-reduce: lanes sharing a row differ only in lg (xor 16,32)
#pragma unroll
    for (int rt = 0; rt < 4; ++rt) {
        float M = m[rt];
        M = fmaxf(M, __shfl_xor(M, 16, 64));
        M = fmaxf(M, __shfl_xor(M, 32, 64));
        float sc = s[rt] * __builtin_amdgcn_exp2f(fmaf(m[rt], CSC, M * NCSC));
        sc += __shfl_xor(sc, 16, 64);
        sc += __shfl_xor(sc, 32, 64);
        if (lg == 0) {
            const int row = (RT0 + rt) * 16 + lr;
            pm[blockIdx.y * N_TOT + row] = M;
            ps[blockIdx.y * N_TOT + row] = sc;
        }
    }
}

// ---------- kernel 3: merge col-group partials, row loss, mean (32 blocks) ----------
__global__ __launch_bounds__(256)
void rowloss_mean_kernel(const float* __restrict__ pm, const float* __restrict__ ps,
                         const float* __restrict__ rowpos, float* __restrict__ out) {
    const int row = blockIdx.x * 256 + threadIdx.x;
    float M = pm[row], S = ps[row];
#pragma unroll
    for (int c = 1; c < CS; ++c) {
        const float Mo = pm[c * N_TOT + row], So = ps[c * N_TOT + row];
        const float mn = fmaxf(M, Mo);
        S = fmaf(S,  __builtin_amdgcn_exp2f(fmaf(M,  CSC, mn * NCSC)),
                 So * __builtin_amdgcn_exp2f(fmaf(Mo, CSC, mn * NCSC)));
        M = mn;
    }
    float acc = LN2F * fmaf(M, CSC, __builtin_amdgcn_logf(S)) - rowpos[row] * INV_T;
#pragma unroll
    for (int off = 32; off > 0; off >>= 1) acc += __shfl_xor(acc, off, 64);
    __shared__ float ls[4];
    if ((threadIdx.x & 63) == 0) ls[threadIdx.x >> 6] = acc;
    __syncthreads();
    if (threadIdx.x == 0)
        atomicAdd(out, (ls[0] + ls[1] + ls[2] + ls[3]) * (1.0f / (float)N_TOT));
}

extern "C" void kernel_launch(void* const* d_in, const int* in_sizes, int n_in,
                              void* d_out, int out_size, void* d_ws, size_t ws_size,
                              hipStream_t stream) {
    const float* feat = (const float*)d_in[0];
    char* ws = (char*)d_ws;
    unsigned short* fbP = (unsigned short*)ws;                                  // 2 MB
    float* pm      = (float*)(ws + (size_t)N_TOT * D * 2);                      // 512 KB
    float* ps      = (float*)(ws + (size_t)N_TOT * D * 2 + (size_t)CS * N_TOT * 4);       // 512 KB
    float* rowpos  = (float*)(ws + (size_t)N_TOT * D * 2 + 2 * (size_t)CS * N_TOT * 4);   // 32 KB
    float* out = (float*)d_out;

    cvt_kernel<<<512, 256, 0, stream>>>(feat, fbP, out);
    simclr_kernel<<<dim3(32, CS), 256, 0, stream>>>(fbP, pm, ps, rowpos);
    rowloss_mean_kernel<<<N_TOT / 256, 256, 0, stream>>>(pm, ps, rowpos, out);
}